// Round 6
// baseline (330.082 us; speedup 1.0000x reference)
//
#include <hip/hip_runtime.h>
#include <math.h>

#define R_ 4
#define TOTAL_ 32768
#define NNODE_ 1024
#define B_ 32
#define DH_ 256
#define C_ 8
#define H_ 8
#define NCLS_ 10
#define E_ 262144
#define S_ 32            // sub-blocks per relation for histogram/scatter
#define CHUNK_ (E_ / S_) // 8192 edges per sub-block

typedef __attribute__((ext_vector_type(4))) float f32x4;
typedef __attribute__((ext_vector_type(2))) float f32x2;
typedef __attribute__((ext_vector_type(2))) unsigned int uint2v;
typedef __attribute__((ext_vector_type(4))) unsigned int uint4v;
typedef long long i64;

__device__ inline unsigned short f2bf(float f) {
  unsigned int u = __builtin_bit_cast(unsigned int, f);
  u += 0x7FFF + ((u >> 16) & 1);
  return (unsigned short)(u >> 16);
}
__device__ inline float bf2f(unsigned short s) {
  return __builtin_bit_cast(float, (unsigned int)s << 16);
}

// ---------------- graph prep (atomic-free CSR build) ----------------

__global__ __launch_bounds__(1024) void hist_part(const int* __restrict__ src,
                                                  const int* __restrict__ dst,
                                                  unsigned int* __restrict__ parts) {
  int r = blockIdx.y, s = blockIdx.x, t = threadIdx.x;
  __shared__ unsigned int hs[16384], hd[16384];
  for (int i = t; i < 16384; i += 1024) { hs[i] = 0; hd[i] = 0; }
  __syncthreads();
  const int* sp = src + (size_t)r * E_ + s * CHUNK_;
  const int* dp = dst + (size_t)r * E_ + s * CHUNK_;
  for (int i = t; i < CHUNK_; i += 1024) {
    int a = sp[i], b = dp[i];
    atomicAdd(&hs[a >> 1], 1u << ((a & 1) * 16));
    atomicAdd(&hd[b >> 1], 1u << ((b & 1) * 16));
  }
  __syncthreads();
  unsigned int* po = parts + ((size_t)(r * S_ + s) * 2) * 16384;
  for (int i = t; i < 16384; i += 1024) { po[i] = hs[i]; po[16384 + i] = hd[i]; }
}

__global__ void reduce_deg(const unsigned int* __restrict__ parts,
                           float* __restrict__ rs_out, float* __restrict__ rs_in,
                           int* __restrict__ cnt_in) {
  int gid = blockIdx.x * 256 + threadIdx.x;  // 0..65535
  int r = gid >> 14, w = gid & 16383;
  unsigned int s0 = 0, s1 = 0, d0 = 0, d1 = 0;
  for (int s = 0; s < S_; s++) {
    unsigned int ws_ = parts[((size_t)(r * S_ + s) * 2) * 16384 + w];
    unsigned int wd  = parts[((size_t)(r * S_ + s) * 2 + 1) * 16384 + w];
    s0 += ws_ & 0xffff; s1 += ws_ >> 16;
    d0 += wd & 0xffff;  d1 += wd >> 16;
  }
  int n0 = w * 2, n1 = n0 + 1;
  rs_out[r * TOTAL_ + n0] = rsqrtf((float)(s0 + 1));
  rs_out[r * TOTAL_ + n1] = rsqrtf((float)(s1 + 1));
  rs_in[r * TOTAL_ + n0]  = rsqrtf((float)(d0 + 1));
  rs_in[r * TOTAL_ + n1]  = rsqrtf((float)(d1 + 1));
  cnt_in[r * TOTAL_ + n0] = (int)d0;
  cnt_in[r * TOTAL_ + n1] = (int)d1;
}

__global__ __launch_bounds__(1024) void scan_counts(const int* __restrict__ cnt_in,
                                                    int* __restrict__ off) {
  int r = blockIdx.x;
  const int* c = cnt_in + r * TOTAL_;
  int* o = off + r * (TOTAL_ + 1);
  __shared__ int part[1024];
  int t = threadIdx.x;
  int base = t * 32;
  int loc[32];
  int s = 0;
#pragma unroll
  for (int j = 0; j < 32; j++) { loc[j] = c[base + j]; s += loc[j]; }
  part[t] = s;
  __syncthreads();
  for (int d = 1; d < 1024; d <<= 1) {
    int v = (t >= d) ? part[t - d] : 0;
    __syncthreads();
    part[t] += v;
    __syncthreads();
  }
  int run = (t == 0) ? 0 : part[t - 1];
#pragma unroll
  for (int j = 0; j < 32; j++) {
    o[base + j] = run;
    run += loc[j];
  }
  if (t == 1023) o[TOTAL_] = run;
}

__global__ void base_gen(const unsigned int* __restrict__ parts,
                         const int* __restrict__ csr_off,
                         unsigned int* __restrict__ sbb) {
  int gid = blockIdx.x * 256 + threadIdx.x;  // 0..65535
  int r = gid >> 14, w = gid & 16383;
  int n0 = w * 2, n1 = n0 + 1;
  unsigned int run0 = (unsigned int)csr_off[r * (TOTAL_ + 1) + n0];
  unsigned int run1 = (unsigned int)csr_off[r * (TOTAL_ + 1) + n1];
  for (int s = 0; s < S_; s++) {
    unsigned int wd = parts[((size_t)(r * S_ + s) * 2 + 1) * 16384 + w];
    sbb[(size_t)(r * S_ + s) * TOTAL_ + n0] = run0;
    sbb[(size_t)(r * S_ + s) * TOTAL_ + n1] = run1;
    run0 += wd & 0xffff;
    run1 += wd >> 16;
  }
}

__global__ __launch_bounds__(1024) void scatter_csr(const int* __restrict__ src,
                                                    const int* __restrict__ dst,
                                                    const unsigned int* __restrict__ sbb,
                                                    int* __restrict__ csr_src) {
  int r = blockIdx.y, s = blockIdx.x, t = threadIdx.x;
  __shared__ unsigned int basel[TOTAL_];
  const unsigned int* sb = sbb + (size_t)(r * S_ + s) * TOTAL_;
  for (int i = t; i < TOTAL_; i += 1024) basel[i] = sb[i];
  __syncthreads();
  const int* sp = src + (size_t)r * E_ + s * CHUNK_;
  const int* dp = dst + (size_t)r * E_ + s * CHUNK_;
  int* co = csr_src + (size_t)r * E_;
  for (int i = t; i < CHUNK_; i += 1024) {
    int d = dp[i];
    unsigned int slot = atomicAdd(&basel[d], 1u);
    co[slot] = sp[i];
  }
}

// ---------------- conversions ----------------

__global__ void hconv8(const float* __restrict__ x, unsigned int* __restrict__ xq) {
  size_t i = (size_t)blockIdx.x * blockDim.x + threadIdx.x;
  float4 a = ((const float4*)x)[2 * i];
  float4 b = ((const float4*)x)[2 * i + 1];
  unsigned int lo = 0, hi = 0;
  lo = __builtin_amdgcn_cvt_pk_fp8_f32(a.x, a.y, lo, false);
  lo = __builtin_amdgcn_cvt_pk_fp8_f32(a.z, a.w, lo, true);
  hi = __builtin_amdgcn_cvt_pk_fp8_f32(b.x, b.y, hi, false);
  hi = __builtin_amdgcn_cvt_pk_fp8_f32(b.z, b.w, hi, true);
  uint2v o; o[0] = lo; o[1] = hi;
  *(uint2v*)&xq[2 * i] = o;
}

// stacked W [1024,256] f32 -> fp8 transposed [256 cols][1024 k], both layers.
// thread -> (layer, col c, k-quad kq): reads 4 strided f32, writes one uint.
__global__ void wconv_f8(const float* __restrict__ W1, const float* __restrict__ W2,
                         unsigned int* __restrict__ T1, unsigned int* __restrict__ T2) {
  int id = blockIdx.x * blockDim.x + threadIdx.x;  // 0..131071
  const float* W = (id < 65536) ? W1 : W2;
  unsigned int* T = (id < 65536) ? T1 : T2;
  int j = id & 65535;
  int c = j >> 8, kq = j & 255;
  int k0 = kq * 4;
  float w0 = W[(size_t)(k0 + 0) * 256 + c];
  float w1 = W[(size_t)(k0 + 1) * 256 + c];
  float w2 = W[(size_t)(k0 + 2) * 256 + c];
  float w3 = W[(size_t)(k0 + 3) * 256 + c];
  unsigned int o = 0;
  o = __builtin_amdgcn_cvt_pk_fp8_f32(w0, w1, o, false);
  o = __builtin_amdgcn_cvt_pk_fp8_f32(w2, w3, o, true);
  T[(size_t)c * 256 + kq] = o;
}

__global__ void bias_sum2(const float* __restrict__ b1, const float* __restrict__ b2,
                          float* __restrict__ s1, float* __restrict__ s2) {
  const float* b = blockIdx.x ? b2 : b1;
  float* s = blockIdx.x ? s2 : s1;
  int d = threadIdx.x;
  s[d] = b[d] + b[DH_ + d] + b[2 * DH_ + d] + b[3 * DH_ + d];
}

// transpose Wr (8 mats) + lin_w (1 mat), each 256x256
__global__ void transpose_mats(const float* __restrict__ Wr, const float* __restrict__ lw,
                               float* __restrict__ Wrt, float* __restrict__ lwt) {
  int i = blockIdx.x * blockDim.x + threadIdx.x;  // 9*65536
  int m = i >> 16, j = i & 65535;
  int row = j >> 8, col = j & 255;
  float v = (m < 8) ? Wr[(size_t)m * 65536 + j] : lw[j];
  float* T = (m < 8) ? (Wrt + (size_t)m * 65536) : lwt;
  T[col * 256 + row] = v;
}

// ---------------- aggregation: one wave per (node, relation) ----------------
// 64 lanes x 4B = one 256B fp8 row per load; edge loop wave-uniform; 4-way MLP.
__global__ __launch_bounds__(256) void aggregate_f8(
    const unsigned int* __restrict__ xq, const int* __restrict__ csr_off,
    const int* __restrict__ csr_src, const float* __restrict__ rs_out,
    const float* __restrict__ rs_in, unsigned int* __restrict__ aggQ) {
  int r = blockIdx.y;
  int node = blockIdx.x * 4 + (threadIdx.x >> 6);
  int lane = threadIdx.x & 63;
  const int* offr = csr_off + r * (TOTAL_ + 1);
  const int* srcs = csr_src + (size_t)r * E_;
  const float* rso = rs_out + r * TOTAL_;
  float a0, a1, a2, a3;
  {
    unsigned int v = xq[(size_t)node * 64 + lane];
    float w = rso[node];
    f32x2 p0 = __builtin_amdgcn_cvt_pk_f32_fp8(v, false);
    f32x2 p1 = __builtin_amdgcn_cvt_pk_f32_fp8(v, true);
    a0 = p0[0] * w; a1 = p0[1] * w; a2 = p1[0] * w; a3 = p1[1] * w;
  }
  int e0 = offr[node], e1 = offr[node + 1];
  int e = e0;
  for (; e + 4 <= e1; e += 4) {
    int s0 = srcs[e], s1 = srcs[e + 1], s2 = srcs[e + 2], s3 = srcs[e + 3];
    unsigned int v0 = xq[(size_t)s0 * 64 + lane];
    unsigned int v1 = xq[(size_t)s1 * 64 + lane];
    unsigned int v2 = xq[(size_t)s2 * 64 + lane];
    unsigned int v3 = xq[(size_t)s3 * 64 + lane];
    float w0 = rso[s0], w1 = rso[s1], w2 = rso[s2], w3 = rso[s3];
    f32x2 p;
    p = __builtin_amdgcn_cvt_pk_f32_fp8(v0, false); a0 += p[0] * w0; a1 += p[1] * w0;
    p = __builtin_amdgcn_cvt_pk_f32_fp8(v0, true);  a2 += p[0] * w0; a3 += p[1] * w0;
    p = __builtin_amdgcn_cvt_pk_f32_fp8(v1, false); a0 += p[0] * w1; a1 += p[1] * w1;
    p = __builtin_amdgcn_cvt_pk_f32_fp8(v1, true);  a2 += p[0] * w1; a3 += p[1] * w1;
    p = __builtin_amdgcn_cvt_pk_f32_fp8(v2, false); a0 += p[0] * w2; a1 += p[1] * w2;
    p = __builtin_amdgcn_cvt_pk_f32_fp8(v2, true);  a2 += p[0] * w2; a3 += p[1] * w2;
    p = __builtin_amdgcn_cvt_pk_f32_fp8(v3, false); a0 += p[0] * w3; a1 += p[1] * w3;
    p = __builtin_amdgcn_cvt_pk_f32_fp8(v3, true);  a2 += p[0] * w3; a3 += p[1] * w3;
  }
  for (; e < e1; e++) {
    int s0 = srcs[e];
    unsigned int v0 = xq[(size_t)s0 * 64 + lane];
    float w0 = rso[s0];
    f32x2 p;
    p = __builtin_amdgcn_cvt_pk_f32_fp8(v0, false); a0 += p[0] * w0; a1 += p[1] * w0;
    p = __builtin_amdgcn_cvt_pk_f32_fp8(v0, true);  a2 += p[0] * w0; a3 += p[1] * w0;
  }
  float wi = rs_in[r * TOTAL_ + node];
  unsigned int o = 0;
  o = __builtin_amdgcn_cvt_pk_fp8_f32(a0 * wi, a1 * wi, o, false);
  o = __builtin_amdgcn_cvt_pk_fp8_f32(a2 * wi, a3 * wi, o, true);
  aggQ[(size_t)node * 256 + r * 64 + lane] = o;
}

// ---------------- fp8 MFMA GEMM: C[32768,256] = A[32768,1024] @ W ----------------
// A, Bt fp8 (Bt = W^T [256 cols][1024 k]). 128x128 tile, BK=64 bytes.
// MODE 0: out8 = fp8(relu(acc+bias)); MODE 1: out16 = bf16(acc+bias).
template <int MODE>
__global__ __launch_bounds__(256) void gemm_f8(
    const unsigned char* __restrict__ A, const unsigned char* __restrict__ Bt,
    const float* __restrict__ bias, unsigned char* __restrict__ out8,
    unsigned short* __restrict__ out16) {
  __shared__ unsigned char As[128][80];  // 80B stride: 16B-aligned, bank-spread
  __shared__ unsigned char Bs[128][80];
  int t = threadIdx.x;
  int row0 = blockIdx.x * 128, col0 = blockIdx.y * 128;
  int wid = t >> 6, lane = t & 63;
  int wm = wid >> 1, wn = wid & 1;
  int lr = lane & 15, lk = lane >> 4;
  f32x4 acc[4][4] = {};
  for (int k0 = 0; k0 < 1024; k0 += 64) {
#pragma unroll
    for (int i = 0; i < 2; i++) {
      int c = t + 256 * i;           // 0..511 chunks of 16B
      int rr = c >> 2, cc = (c & 3) * 16;
      *(uint4v*)&As[rr][cc] = *(const uint4v*)&A[(size_t)(row0 + rr) * 1024 + k0 + cc];
      *(uint4v*)&Bs[rr][cc] = *(const uint4v*)&Bt[(size_t)(col0 + rr) * 1024 + k0 + cc];
    }
    __syncthreads();
#pragma unroll
    for (int kk = 0; kk < 2; kk++) {
      i64 afr[4], bfr[4];
#pragma unroll
      for (int m = 0; m < 4; m++) afr[m] = *(const i64*)&As[wm * 64 + m * 16 + lr][kk * 32 + lk * 8];
#pragma unroll
      for (int n = 0; n < 4; n++) bfr[n] = *(const i64*)&Bs[wn * 64 + n * 16 + lr][kk * 32 + lk * 8];
#pragma unroll
      for (int m = 0; m < 4; m++)
#pragma unroll
        for (int n = 0; n < 4; n++)
          acc[m][n] = __builtin_amdgcn_mfma_f32_16x16x32_fp8_fp8(afr[m], bfr[n], acc[m][n], 0, 0, 0);
    }
    __syncthreads();
  }
  int lq = lane >> 4;
#pragma unroll
  for (int m = 0; m < 4; m++) {
    int row = row0 + wm * 64 + m * 16 + lq * 4;
#pragma unroll
    for (int n = 0; n < 4; n++) {
      int col = col0 + wn * 64 + n * 16 + lr;
      float bv = bias[col];
#pragma unroll
      for (int q = 0; q < 4; q++) {
        float v = acc[m][n][q] + bv;
        if (MODE == 0) {
          v = fmaxf(v, 0.f);
          int b8 = __builtin_amdgcn_cvt_pk_fp8_f32(v, 0.f, 0, false);
          out8[(size_t)(row + q) * DH_ + col] = (unsigned char)b8;
        } else {
          out16[(size_t)(row + q) * DH_ + col] = f2bf(v);
        }
      }
    }
  }
}

// ---------------- pooling (2-phase, bf16 h2) ----------------

__global__ __launch_bounds__(256) void pool_part(const unsigned short* __restrict__ h2b,
                                                 const int* __restrict__ node_label,
                                                 float* __restrict__ part) {
  int b = blockIdx.x, ch = blockIdx.y, d = threadIdx.x;
  __shared__ int slab[128];
  if (d < 128) slab[d] = node_label[ch * 128 + d];
  __syncthreads();
  float a[C_] = {0.f};
  float at = 0.f;
  const unsigned short* base = h2b + ((size_t)b * NNODE_ + ch * 128) * DH_ + d;
  for (int n = 0; n < 128; n++) {
    float x = bf2f(base[(size_t)n * DH_]);
    int lab = slab[n];
    at += x;
#pragma unroll
    for (int k = 0; k < C_; k++) a[k] += (lab == k) ? x : 0.f;
  }
  float* pb = part + ((size_t)(ch * B_ + b) * 9) * DH_ + d;
#pragma unroll
  for (int k = 0; k < C_; k++) pb[(size_t)k * DH_] = a[k];
  pb[(size_t)8 * DH_] = at;
}

__global__ __launch_bounds__(256) void pool_fin(const float* __restrict__ part,
                                                const int* __restrict__ node_label,
                                                const int* __restrict__ feat_label,
                                                float* __restrict__ poolv,
                                                float* __restrict__ hg_raw) {
  int b = blockIdx.x, d = threadIdx.x;
  __shared__ int cnt[C_];
  if (d < C_) cnt[d] = 0;
  __syncthreads();
  for (int n = d; n < NNODE_; n += 256) atomicAdd(&cnt[node_label[n]], 1);
  __syncthreads();
  float s[9];
#pragma unroll
  for (int k = 0; k < 9; k++) s[k] = 0.f;
  for (int ch = 0; ch < 8; ch++) {
    const float* pb = part + ((size_t)(ch * B_ + b) * 9) * DH_ + d;
#pragma unroll
    for (int k = 0; k < 9; k++) s[k] += pb[(size_t)k * DH_];
  }
  int fl = feat_label[d];
#pragma unroll
  for (int k = 0; k < C_; k++) {
    float cntf = fmaxf((float)cnt[k], 1.f);
    float v = (fl == k) ? (s[k] / cntf) : 0.f;
    poolv[((size_t)k * B_ + b) * DH_ + d] = v;
  }
  hg_raw[(size_t)b * DH_ + d] = s[8] * (1.f / NNODE_);
}

// ---------------- tail ----------------

// fused resize + qkv: grid B*C
__global__ __launch_bounds__(256) void rq_t(const float* __restrict__ poolv,
                                            const float* __restrict__ Wrt,
                                            const float* __restrict__ br,
                                            const float* __restrict__ Wq,
                                            const float* __restrict__ Wk,
                                            const float* __restrict__ Wv,
                                            float* __restrict__ emb,
                                            float* __restrict__ q, float* __restrict__ k,
                                            float* __restrict__ v) {
  int key = blockIdx.x & 7, b = blockIdx.x >> 3, t = threadIdx.x;
  __shared__ float pl[DH_], es[DH_];
  pl[t] = poolv[((size_t)key * B_ + b) * DH_ + t];
  __syncthreads();
  const float* W = Wrt + (size_t)key * DH_ * DH_;
  float s = 0.f;
  for (int d = 0; d < DH_; d++) s += pl[d] * W[d * DH_ + t];
  s += br[key * DH_ + t];
  es[t] = s;
  size_t idx = (size_t)b * C_ + key;
  emb[idx * DH_ + t] = s;
  __syncthreads();
  float sq = 0.f, sk = 0.f, sv = 0.f;
  for (int kk = 0; kk < DH_; kk++) {
    float xv = es[kk];
    sq += xv * Wq[kk * DH_ + t];
    sk += xv * Wk[kk * DH_ + t];
    sv += xv * Wv[kk * DH_ + t];
  }
  q[idx * DH_ + t] = sq;
  k[idx * DH_ + t] = sk;
  v[idx * DH_ + t] = sv;
}

__global__ __launch_bounds__(256) void attn_core(const float* __restrict__ q,
                                                 const float* __restrict__ k,
                                                 const float* __restrict__ v,
                                                 float* __restrict__ osb) {
  int b = blockIdx.x, t = threadIdx.x;
  __shared__ float qs[C_][DH_], ks[C_][DH_], vs[C_][DH_];
  __shared__ float sc[H_][C_][C_];
  for (int c = 0; c < C_; c++) {
    qs[c][t] = q[((size_t)b * C_ + c) * DH_ + t];
    ks[c][t] = k[((size_t)b * C_ + c) * DH_ + t];
    vs[c][t] = v[((size_t)b * C_ + c) * DH_ + t];
  }
  __syncthreads();
  for (int idx = t; idx < H_ * C_ * C_; idx += 256) {
    int hh = idx / (C_ * C_);
    int qc = (idx / C_) % C_;
    int kc = idx % C_;
    float s = 0.f;
    for (int dd = 0; dd < 32; dd++) s += qs[qc][hh * 32 + dd] * ks[kc][hh * 32 + dd];
    sc[hh][qc][kc] = s * 0.35355339059327373f;
  }
  __syncthreads();
  if (t < H_ * C_) {
    int hh = t / C_, qc = t % C_;
    float m = -1e30f;
    for (int kc = 0; kc < C_; kc++) m = fmaxf(m, sc[hh][qc][kc]);
    float sum = 0.f;
    for (int kc = 0; kc < C_; kc++) { float e = expf(sc[hh][qc][kc] - m); sc[hh][qc][kc] = e; sum += e; }
    float inv = 1.f / sum;
    for (int kc = 0; kc < C_; kc++) sc[hh][qc][kc] *= inv;
  }
  __syncthreads();
  int hh = t >> 5;
  for (int c = 0; c < C_; c++) {
    float s = 0.f;
#pragma unroll
    for (int kc = 0; kc < C_; kc++) s += sc[hh][c][kc] * vs[kc][t];
    osb[((size_t)b * C_ + c) * DH_ + t] = s;
  }
}

__global__ __launch_bounds__(256) void ff_res(const float* __restrict__ osb,
                                              const float* __restrict__ emb,
                                              const float* __restrict__ lwt,
                                              const float* __restrict__ lb,
                                              float* __restrict__ ffb) {
  int idx = blockIdx.x, t = threadIdx.x;
  __shared__ float ox[DH_];
  ox[t] = osb[(size_t)idx * DH_ + t];
  __syncthreads();
  float s = 0.f;
  for (int d = 0; d < DH_; d++) s += ox[d] * lwt[d * DH_ + t];
  ffb[(size_t)idx * DH_ + t] =
      fmaxf(s + lb[t], 0.f) + ox[t] + emb[(size_t)idx * DH_ + t];
}

__global__ __launch_bounds__(256) void tail_final(
    const float* __restrict__ ffb, const float* __restrict__ hg_raw,
    const float* __restrict__ g, const float* __restrict__ be,
    const float* __restrict__ cw, const float* __restrict__ cb,
    float* __restrict__ out) {
  int t = threadIdx.x;
  __shared__ float hgn[B_][DH_];
  __shared__ float red[256];
  float gcol[B_];
  float mu = 0.f;
#pragma unroll
  for (int b = 0; b < B_; b++) {
    float s = 0.f;
    for (int c = 0; c < C_; c++) s += ffb[((size_t)b * C_ + c) * DH_ + t];
    gcol[b] = s * (1.f / C_);
    mu += gcol[b];
  }
  mu *= (1.f / B_);
  float var = 0.f;
#pragma unroll
  for (int b = 0; b < B_; b++) { float x = gcol[b] - mu; var += x * x; }
  var *= (1.f / B_);
  float is = rsqrtf(var + 1e-5f);
  float gm = g[t], bt = be[t];
  float s = 0.f;
#pragma unroll
  for (int b = 0; b < B_; b++) {
    hgn[b][t] = (gcol[b] - mu) * is * gm + bt;
    float d = gcol[b] - hg_raw[b * DH_ + t] + 1e-6f;
    s += d * d;
  }
  red[t] = s;
  __syncthreads();
  for (int w = 128; w > 0; w >>= 1) {
    if (t < w) red[t] += red[t + w];
    __syncthreads();
  }
  if (t == 0) out[B_ * NCLS_] = sqrtf(red[0]);
  for (int o = t; o < B_ * NCLS_; o += 256) {
    int b = o / NCLS_, j = o % NCLS_;
    float sl = cb[j];
    for (int d = 0; d < DH_; d++) sl += hgn[b][d] * cw[j * DH_ + d];
    out[o] = sl;
  }
}

// ---------------- launch ----------------

extern "C" void kernel_launch(void* const* d_in, const int* in_sizes, int n_in,
                              void* d_out, int out_size, void* d_ws, size_t ws_size,
                              hipStream_t stream) {
  const float* h   = (const float*)d_in[0];
  const int* src   = (const int*)d_in[1];
  const int* dst   = (const int*)d_in[2];
  const int* nlab  = (const int*)d_in[3];
  const int* flab  = (const int*)d_in[4];
  const float* W1  = (const float*)d_in[5];
  const float* b1  = (const float*)d_in[6];
  const float* W2  = (const float*)d_in[7];
  const float* b2  = (const float*)d_in[8];
  const float* Wr  = (const float*)d_in[9];
  const float* br  = (const float*)d_in[10];
  const float* Wq  = (const float*)d_in[11];
  const float* Wk  = (const float*)d_in[12];
  const float* Wv  = (const float*)d_in[13];
  const float* lw  = (const float*)d_in[14];
  const float* lb  = (const float*)d_in[15];
  const float* bng = (const float*)d_in[16];
  const float* bnb = (const float*)d_in[17];
  const float* cw  = (const float*)d_in[18];
  const float* cb  = (const float*)d_in[19];
  float* out = (float*)d_out;

  char* p = (char*)d_ws;
  auto alloc = [&](size_t bytes) -> void* {
    void* q = (void*)p;
    p += (bytes + 255) & ~(size_t)255;
    return q;
  };
  unsigned int* xq    = (unsigned int*)alloc((size_t)TOTAL_ * DH_);       // 8MB fp8
  unsigned int* h1q   = (unsigned int*)alloc((size_t)TOTAL_ * DH_);       // 8MB fp8
  unsigned short* h2b = (unsigned short*)alloc((size_t)TOTAL_ * DH_ * 2); // 16MB bf16
  unsigned int* aggQ  = (unsigned int*)alloc((size_t)TOTAL_ * 1024);      // 32MB fp8
  unsigned int* Wq1   = (unsigned int*)alloc((size_t)256 * 256 * 4);      // fp8 W1^T
  unsigned int* Wq2   = (unsigned int*)alloc((size_t)256 * 256 * 4);      // fp8 W2^T
  float* Wrt   = (float*)alloc((size_t)C_ * DH_ * DH_ * 4);
  float* lwt   = (float*)alloc((size_t)DH_ * DH_ * 4);
  float* bsum1 = (float*)alloc(DH_ * 4);
  float* bsum2 = (float*)alloc(DH_ * 4);
  int* cnt_in   = (int*)alloc((size_t)R_ * TOTAL_ * 4);
  float* rs_out = (float*)alloc((size_t)R_ * TOTAL_ * 4);
  float* rs_in  = (float*)alloc((size_t)R_ * TOTAL_ * 4);
  int* csr_off  = (int*)alloc((size_t)R_ * (TOTAL_ + 1) * 4);
  int* csr_src  = (int*)alloc((size_t)R_ * E_ * 4);
  float* part   = (float*)alloc((size_t)8 * B_ * 9 * DH_ * 4);
  float* poolv  = (float*)alloc((size_t)C_ * B_ * DH_ * 4);
  float* hg_raw = (float*)alloc((size_t)B_ * DH_ * 4);
  float* emb    = (float*)alloc((size_t)B_ * C_ * DH_ * 4);
  float* qb     = (float*)alloc((size_t)B_ * C_ * DH_ * 4);
  float* kb     = (float*)alloc((size_t)B_ * C_ * DH_ * 4);
  float* vb     = (float*)alloc((size_t)B_ * C_ * DH_ * 4);
  float* osb    = (float*)alloc((size_t)B_ * C_ * DH_ * 4);
  float* ffb    = (float*)alloc((size_t)B_ * C_ * DH_ * 4);

  // prep-phase scratch aliased onto aggQ (dead until aggregation)
  unsigned int* parts = aggQ;                                                   // 16MB
  unsigned int* sbb   = (unsigned int*)((char*)aggQ + (size_t)16 * 1024 * 1024); // 16MB

  // graph prep (no global atomics)
  hist_part<<<dim3(S_, R_), 1024, 0, stream>>>(src, dst, parts);
  reduce_deg<<<R_ * TOTAL_ / 512, 256, 0, stream>>>(parts, rs_out, rs_in, cnt_in);
  scan_counts<<<R_, 1024, 0, stream>>>(cnt_in, csr_off);
  base_gen<<<R_ * TOTAL_ / 512, 256, 0, stream>>>(parts, csr_off, sbb);
  scatter_csr<<<dim3(S_, R_), 1024, 0, stream>>>(src, dst, sbb, csr_src);

  // weight/bias/input prep
  wconv_f8<<<512, 256, 0, stream>>>(W1, W2, Wq1, Wq2);
  bias_sum2<<<2, 256, 0, stream>>>(b1, b2, bsum1, bsum2);
  transpose_mats<<<9 * 256, 256, 0, stream>>>(Wr, lw, Wrt, lwt);
  hconv8<<<TOTAL_ * DH_ / 8 / 256, 256, 0, stream>>>(h, xq);

  // layer 1
  aggregate_f8<<<dim3(TOTAL_ / 4, R_), 256, 0, stream>>>(xq, csr_off, csr_src, rs_out, rs_in, aggQ);
  gemm_f8<0><<<dim3(TOTAL_ / 128, 2), 256, 0, stream>>>(
      (const unsigned char*)aggQ, (const unsigned char*)Wq1, bsum1,
      (unsigned char*)h1q, nullptr);

  // layer 2
  aggregate_f8<<<dim3(TOTAL_ / 4, R_), 256, 0, stream>>>(h1q, csr_off, csr_src, rs_out, rs_in, aggQ);
  gemm_f8<1><<<dim3(TOTAL_ / 128, 2), 256, 0, stream>>>(
      (const unsigned char*)aggQ, (const unsigned char*)Wq2, bsum2,
      nullptr, h2b);

  // pooling + tail
  pool_part<<<dim3(B_, 8), 256, 0, stream>>>(h2b, nlab, part);
  pool_fin<<<B_, 256, 0, stream>>>(part, nlab, flab, poolv, hg_raw);
  rq_t<<<B_ * C_, 256, 0, stream>>>(poolv, Wrt, br, Wq, Wk, Wv, emb, qb, kb, vb);
  attn_core<<<B_, 256, 0, stream>>>(qb, kb, vb, osb);
  ff_res<<<B_ * C_, 256, 0, stream>>>(osb, emb, lwt, lb, ffb);
  tail_final<<<1, 256, 0, stream>>>(ffb, hg_raw, bng, bnb, cw, cb, out);
}

// Round 7
// 300.394 us; speedup vs baseline: 1.0988x; 1.0988x over previous
//
#include <hip/hip_runtime.h>
#include <math.h>

#define R_ 4
#define TOTAL_ 32768
#define NNODE_ 1024
#define B_ 32
#define DH_ 256
#define C_ 8
#define H_ 8
#define NCLS_ 10
#define E_ 262144
#define S_ 32            // sub-blocks per relation for histogram/scatter
#define CHUNK_ (E_ / S_) // 8192 edges per sub-block

typedef __attribute__((ext_vector_type(4))) float f32x4;
typedef __attribute__((ext_vector_type(2))) float f32x2;
typedef __attribute__((ext_vector_type(2))) unsigned int uint2v;
typedef __attribute__((ext_vector_type(4))) unsigned int uint4v;
typedef long long i64;

__device__ inline unsigned short f2bf(float f) {
  unsigned int u = __builtin_bit_cast(unsigned int, f);
  u += 0x7FFF + ((u >> 16) & 1);
  return (unsigned short)(u >> 16);
}
__device__ inline float bf2f(unsigned short s) {
  return __builtin_bit_cast(float, (unsigned int)s << 16);
}

// ---------------- graph prep (atomic-free CSR build) ----------------

__global__ __launch_bounds__(1024) void hist_part(const int* __restrict__ src,
                                                  const int* __restrict__ dst,
                                                  unsigned int* __restrict__ parts) {
  int r = blockIdx.y, s = blockIdx.x, t = threadIdx.x;
  __shared__ unsigned int hs[16384], hd[16384];
  for (int i = t; i < 16384; i += 1024) { hs[i] = 0; hd[i] = 0; }
  __syncthreads();
  const int* sp = src + (size_t)r * E_ + s * CHUNK_;
  const int* dp = dst + (size_t)r * E_ + s * CHUNK_;
  for (int i = t; i < CHUNK_; i += 1024) {
    int a = sp[i], b = dp[i];
    atomicAdd(&hs[a >> 1], 1u << ((a & 1) * 16));
    atomicAdd(&hd[b >> 1], 1u << ((b & 1) * 16));
  }
  __syncthreads();
  unsigned int* po = parts + ((size_t)(r * S_ + s) * 2) * 16384;
  for (int i = t; i < 16384; i += 1024) { po[i] = hs[i]; po[16384 + i] = hd[i]; }
}

__global__ void reduce_deg(const unsigned int* __restrict__ parts,
                           float* __restrict__ rs_out, float* __restrict__ rs_in,
                           int* __restrict__ cnt_in) {
  int gid = blockIdx.x * 256 + threadIdx.x;  // 0..65535
  int r = gid >> 14, w = gid & 16383;
  unsigned int s0 = 0, s1 = 0, d0 = 0, d1 = 0;
  for (int s = 0; s < S_; s++) {
    unsigned int ws_ = parts[((size_t)(r * S_ + s) * 2) * 16384 + w];
    unsigned int wd  = parts[((size_t)(r * S_ + s) * 2 + 1) * 16384 + w];
    s0 += ws_ & 0xffff; s1 += ws_ >> 16;
    d0 += wd & 0xffff;  d1 += wd >> 16;
  }
  int n0 = w * 2, n1 = n0 + 1;
  rs_out[r * TOTAL_ + n0] = rsqrtf((float)(s0 + 1));
  rs_out[r * TOTAL_ + n1] = rsqrtf((float)(s1 + 1));
  rs_in[r * TOTAL_ + n0]  = rsqrtf((float)(d0 + 1));
  rs_in[r * TOTAL_ + n1]  = rsqrtf((float)(d1 + 1));
  cnt_in[r * TOTAL_ + n0] = (int)d0;
  cnt_in[r * TOTAL_ + n1] = (int)d1;
}

__global__ __launch_bounds__(1024) void scan_counts(const int* __restrict__ cnt_in,
                                                    int* __restrict__ off) {
  int r = blockIdx.x;
  const int* c = cnt_in + r * TOTAL_;
  int* o = off + r * (TOTAL_ + 1);
  __shared__ int part[1024];
  int t = threadIdx.x;
  int base = t * 32;
  int loc[32];
  int s = 0;
#pragma unroll
  for (int j = 0; j < 32; j++) { loc[j] = c[base + j]; s += loc[j]; }
  part[t] = s;
  __syncthreads();
  for (int d = 1; d < 1024; d <<= 1) {
    int v = (t >= d) ? part[t - d] : 0;
    __syncthreads();
    part[t] += v;
    __syncthreads();
  }
  int run = (t == 0) ? 0 : part[t - 1];
#pragma unroll
  for (int j = 0; j < 32; j++) {
    o[base + j] = run;
    run += loc[j];
  }
  if (t == 1023) o[TOTAL_] = run;
}

__global__ void base_gen(const unsigned int* __restrict__ parts,
                         const int* __restrict__ csr_off,
                         unsigned int* __restrict__ sbb) {
  int gid = blockIdx.x * 256 + threadIdx.x;  // 0..65535
  int r = gid >> 14, w = gid & 16383;
  int n0 = w * 2, n1 = n0 + 1;
  unsigned int run0 = (unsigned int)csr_off[r * (TOTAL_ + 1) + n0];
  unsigned int run1 = (unsigned int)csr_off[r * (TOTAL_ + 1) + n1];
  for (int s = 0; s < S_; s++) {
    unsigned int wd = parts[((size_t)(r * S_ + s) * 2 + 1) * 16384 + w];
    sbb[(size_t)(r * S_ + s) * TOTAL_ + n0] = run0;
    sbb[(size_t)(r * S_ + s) * TOTAL_ + n1] = run1;
    run0 += wd & 0xffff;
    run1 += wd >> 16;
  }
}

__global__ __launch_bounds__(1024) void scatter_csr(const int* __restrict__ src,
                                                    const int* __restrict__ dst,
                                                    const unsigned int* __restrict__ sbb,
                                                    int* __restrict__ csr_src) {
  int r = blockIdx.y, s = blockIdx.x, t = threadIdx.x;
  __shared__ unsigned int basel[TOTAL_];
  const unsigned int* sb = sbb + (size_t)(r * S_ + s) * TOTAL_;
  for (int i = t; i < TOTAL_; i += 1024) basel[i] = sb[i];
  __syncthreads();
  const int* sp = src + (size_t)r * E_ + s * CHUNK_;
  const int* dp = dst + (size_t)r * E_ + s * CHUNK_;
  int* co = csr_src + (size_t)r * E_;
  for (int i = t; i < CHUNK_; i += 1024) {
    int d = dp[i];
    unsigned int slot = atomicAdd(&basel[d], 1u);
    co[slot] = sp[i];
  }
}

// ---------------- conversions ----------------

__global__ void hconv8(const float* __restrict__ x, unsigned int* __restrict__ xq) {
  size_t i = (size_t)blockIdx.x * blockDim.x + threadIdx.x;
  float4 a = ((const float4*)x)[2 * i];
  float4 b = ((const float4*)x)[2 * i + 1];
  unsigned int lo = 0, hi = 0;
  lo = __builtin_amdgcn_cvt_pk_fp8_f32(a.x, a.y, lo, false);
  lo = __builtin_amdgcn_cvt_pk_fp8_f32(a.z, a.w, lo, true);
  hi = __builtin_amdgcn_cvt_pk_fp8_f32(b.x, b.y, hi, false);
  hi = __builtin_amdgcn_cvt_pk_fp8_f32(b.z, b.w, hi, true);
  uint2v o; o[0] = lo; o[1] = hi;
  *(uint2v*)&xq[2 * i] = o;
}

// stacked W [1024,256] f32 -> fp8 transposed [256 cols][1024 k], both layers.
__global__ void wconv_f8(const float* __restrict__ W1, const float* __restrict__ W2,
                         unsigned int* __restrict__ T1, unsigned int* __restrict__ T2) {
  int id = blockIdx.x * blockDim.x + threadIdx.x;  // 0..131071
  const float* W = (id < 65536) ? W1 : W2;
  unsigned int* T = (id < 65536) ? T1 : T2;
  int j = id & 65535;
  int c = j >> 8, kq = j & 255;
  int k0 = kq * 4;
  float w0 = W[(size_t)(k0 + 0) * 256 + c];
  float w1 = W[(size_t)(k0 + 1) * 256 + c];
  float w2 = W[(size_t)(k0 + 2) * 256 + c];
  float w3 = W[(size_t)(k0 + 3) * 256 + c];
  unsigned int o = 0;
  o = __builtin_amdgcn_cvt_pk_fp8_f32(w0, w1, o, false);
  o = __builtin_amdgcn_cvt_pk_fp8_f32(w2, w3, o, true);
  T[(size_t)c * 256 + kq] = o;
}

__global__ void bias_sum2(const float* __restrict__ b1, const float* __restrict__ b2,
                          float* __restrict__ s1, float* __restrict__ s2) {
  const float* b = blockIdx.x ? b2 : b1;
  float* s = blockIdx.x ? s2 : s1;
  int d = threadIdx.x;
  s[d] = b[d] + b[DH_ + d] + b[2 * DH_ + d] + b[3 * DH_ + d];
}

// transpose Wr (8 mats) + lin_w (1 mat), each 256x256
__global__ void transpose_mats(const float* __restrict__ Wr, const float* __restrict__ lw,
                               float* __restrict__ Wrt, float* __restrict__ lwt) {
  int i = blockIdx.x * blockDim.x + threadIdx.x;  // 9*65536
  int m = i >> 16, j = i & 65535;
  int row = j >> 8, col = j & 255;
  float v = (m < 8) ? Wr[(size_t)m * 65536 + j] : lw[j];
  float* T = (m < 8) ? (Wrt + (size_t)m * 65536) : lwt;
  T[col * 256 + row] = v;
}

// ---------------- aggregation: fp8 in/out, 32-lane groups, 4-way unroll ------
// 8 nodes/block; each 32-lane group owns a node; 8B/lane loads (512B/wave-instr)
__global__ __launch_bounds__(256) void aggregate_f8(
    const unsigned int* __restrict__ xq, const int* __restrict__ csr_off,
    const int* __restrict__ csr_src, const float* __restrict__ rs_out,
    const float* __restrict__ rs_in, unsigned int* __restrict__ aggQ) {
  int r = blockIdx.y;
  int node = blockIdx.x * 8 + (threadIdx.x >> 5);
  int lane5 = threadIdx.x & 31;
  const int* offr = csr_off + r * (TOTAL_ + 1);
  const int* srcs = csr_src + (size_t)r * E_;
  const float* rso = rs_out + r * TOTAL_;
  float a0, a1, a2, a3, a4, a5, a6, a7;
  {
    uint2v v = *(const uint2v*)&xq[(size_t)node * 64 + lane5 * 2];
    float w = rso[node];
    f32x2 p;
    p = __builtin_amdgcn_cvt_pk_f32_fp8(v[0], false); a0 = p[0] * w; a1 = p[1] * w;
    p = __builtin_amdgcn_cvt_pk_f32_fp8(v[0], true);  a2 = p[0] * w; a3 = p[1] * w;
    p = __builtin_amdgcn_cvt_pk_f32_fp8(v[1], false); a4 = p[0] * w; a5 = p[1] * w;
    p = __builtin_amdgcn_cvt_pk_f32_fp8(v[1], true);  a6 = p[0] * w; a7 = p[1] * w;
  }
  int e0 = offr[node], e1 = offr[node + 1];
  int e = e0;
  for (; e + 4 <= e1; e += 4) {
    int s0 = srcs[e], s1 = srcs[e + 1], s2 = srcs[e + 2], s3 = srcs[e + 3];
    uint2v v0 = *(const uint2v*)&xq[(size_t)s0 * 64 + lane5 * 2];
    uint2v v1 = *(const uint2v*)&xq[(size_t)s1 * 64 + lane5 * 2];
    uint2v v2 = *(const uint2v*)&xq[(size_t)s2 * 64 + lane5 * 2];
    uint2v v3 = *(const uint2v*)&xq[(size_t)s3 * 64 + lane5 * 2];
    float w0 = rso[s0], w1 = rso[s1], w2 = rso[s2], w3 = rso[s3];
    f32x2 p;
    p = __builtin_amdgcn_cvt_pk_f32_fp8(v0[0], false); a0 += p[0] * w0; a1 += p[1] * w0;
    p = __builtin_amdgcn_cvt_pk_f32_fp8(v0[0], true);  a2 += p[0] * w0; a3 += p[1] * w0;
    p = __builtin_amdgcn_cvt_pk_f32_fp8(v0[1], false); a4 += p[0] * w0; a5 += p[1] * w0;
    p = __builtin_amdgcn_cvt_pk_f32_fp8(v0[1], true);  a6 += p[0] * w0; a7 += p[1] * w0;
    p = __builtin_amdgcn_cvt_pk_f32_fp8(v1[0], false); a0 += p[0] * w1; a1 += p[1] * w1;
    p = __builtin_amdgcn_cvt_pk_f32_fp8(v1[0], true);  a2 += p[0] * w1; a3 += p[1] * w1;
    p = __builtin_amdgcn_cvt_pk_f32_fp8(v1[1], false); a4 += p[0] * w1; a5 += p[1] * w1;
    p = __builtin_amdgcn_cvt_pk_f32_fp8(v1[1], true);  a6 += p[0] * w1; a7 += p[1] * w1;
    p = __builtin_amdgcn_cvt_pk_f32_fp8(v2[0], false); a0 += p[0] * w2; a1 += p[1] * w2;
    p = __builtin_amdgcn_cvt_pk_f32_fp8(v2[0], true);  a2 += p[0] * w2; a3 += p[1] * w2;
    p = __builtin_amdgcn_cvt_pk_f32_fp8(v2[1], false); a4 += p[0] * w2; a5 += p[1] * w2;
    p = __builtin_amdgcn_cvt_pk_f32_fp8(v2[1], true);  a6 += p[0] * w2; a7 += p[1] * w2;
    p = __builtin_amdgcn_cvt_pk_f32_fp8(v3[0], false); a0 += p[0] * w3; a1 += p[1] * w3;
    p = __builtin_amdgcn_cvt_pk_f32_fp8(v3[0], true);  a2 += p[0] * w3; a3 += p[1] * w3;
    p = __builtin_amdgcn_cvt_pk_f32_fp8(v3[1], false); a4 += p[0] * w3; a5 += p[1] * w3;
    p = __builtin_amdgcn_cvt_pk_f32_fp8(v3[1], true);  a6 += p[0] * w3; a7 += p[1] * w3;
  }
  for (; e < e1; e++) {
    int s0 = srcs[e];
    uint2v v0 = *(const uint2v*)&xq[(size_t)s0 * 64 + lane5 * 2];
    float w0 = rso[s0];
    f32x2 p;
    p = __builtin_amdgcn_cvt_pk_f32_fp8(v0[0], false); a0 += p[0] * w0; a1 += p[1] * w0;
    p = __builtin_amdgcn_cvt_pk_f32_fp8(v0[0], true);  a2 += p[0] * w0; a3 += p[1] * w0;
    p = __builtin_amdgcn_cvt_pk_f32_fp8(v0[1], false); a4 += p[0] * w0; a5 += p[1] * w0;
    p = __builtin_amdgcn_cvt_pk_f32_fp8(v0[1], true);  a6 += p[0] * w0; a7 += p[1] * w0;
  }
  float wi = rs_in[r * TOTAL_ + node];
  unsigned int o0 = 0, o1 = 0;
  o0 = __builtin_amdgcn_cvt_pk_fp8_f32(a0 * wi, a1 * wi, o0, false);
  o0 = __builtin_amdgcn_cvt_pk_fp8_f32(a2 * wi, a3 * wi, o0, true);
  o1 = __builtin_amdgcn_cvt_pk_fp8_f32(a4 * wi, a5 * wi, o1, false);
  o1 = __builtin_amdgcn_cvt_pk_fp8_f32(a6 * wi, a7 * wi, o1, true);
  uint2v o; o[0] = o0; o[1] = o1;
  *(uint2v*)&aggQ[(size_t)node * 256 + r * 64 + lane5 * 2] = o;
}

// ---------------- fp8 MFMA GEMM: C[32768,256] = A[32768,1024] @ W ----------------
// A, Bt fp8 (Bt = W^T [256 cols][1024 k]). 128x128 tile, BK=64 bytes.
// MODE 0: out8 = fp8(relu(acc+bias)); MODE 1: out16 = bf16(acc+bias).
template <int MODE>
__global__ __launch_bounds__(256) void gemm_f8(
    const unsigned char* __restrict__ A, const unsigned char* __restrict__ Bt,
    const float* __restrict__ bias, unsigned char* __restrict__ out8,
    unsigned short* __restrict__ out16) {
  __shared__ unsigned char As[128][80];  // 80B stride: 16B-aligned, bank-spread
  __shared__ unsigned char Bs[128][80];
  int t = threadIdx.x;
  int row0 = blockIdx.x * 128, col0 = blockIdx.y * 128;
  int wid = t >> 6, lane = t & 63;
  int wm = wid >> 1, wn = wid & 1;
  int lr = lane & 15, lk = lane >> 4;
  f32x4 acc[4][4] = {};
  for (int k0 = 0; k0 < 1024; k0 += 64) {
#pragma unroll
    for (int i = 0; i < 2; i++) {
      int c = t + 256 * i;           // 0..511 chunks of 16B
      int rr = c >> 2, cc = (c & 3) * 16;
      *(uint4v*)&As[rr][cc] = *(const uint4v*)&A[(size_t)(row0 + rr) * 1024 + k0 + cc];
      *(uint4v*)&Bs[rr][cc] = *(const uint4v*)&Bt[(size_t)(col0 + rr) * 1024 + k0 + cc];
    }
    __syncthreads();
#pragma unroll
    for (int kk = 0; kk < 2; kk++) {
      i64 afr[4], bfr[4];
#pragma unroll
      for (int m = 0; m < 4; m++) afr[m] = *(const i64*)&As[wm * 64 + m * 16 + lr][kk * 32 + lk * 8];
#pragma unroll
      for (int n = 0; n < 4; n++) bfr[n] = *(const i64*)&Bs[wn * 64 + n * 16 + lr][kk * 32 + lk * 8];
#pragma unroll
      for (int m = 0; m < 4; m++)
#pragma unroll
        for (int n = 0; n < 4; n++)
          acc[m][n] = __builtin_amdgcn_mfma_f32_16x16x32_fp8_fp8(afr[m], bfr[n], acc[m][n], 0, 0, 0);
    }
    __syncthreads();
  }
  int lq = lane >> 4;
#pragma unroll
  for (int m = 0; m < 4; m++) {
    int row = row0 + wm * 64 + m * 16 + lq * 4;
#pragma unroll
    for (int n = 0; n < 4; n++) {
      int col = col0 + wn * 64 + n * 16 + lr;
      float bv = bias[col];
#pragma unroll
      for (int q = 0; q < 4; q++) {
        float v = acc[m][n][q] + bv;
        if (MODE == 0) {
          v = fmaxf(v, 0.f);
          int b8 = __builtin_amdgcn_cvt_pk_fp8_f32(v, 0.f, 0, false);
          out8[(size_t)(row + q) * DH_ + col] = (unsigned char)b8;
        } else {
          out16[(size_t)(row + q) * DH_ + col] = f2bf(v);
        }
      }
    }
  }
}

// ---------------- pooling (2-phase, bf16 h2) ----------------

__global__ __launch_bounds__(256) void pool_part(const unsigned short* __restrict__ h2b,
                                                 const int* __restrict__ node_label,
                                                 float* __restrict__ part) {
  int b = blockIdx.x, ch = blockIdx.y, d = threadIdx.x;
  __shared__ int slab[128];
  if (d < 128) slab[d] = node_label[ch * 128 + d];
  __syncthreads();
  float a[C_] = {0.f};
  float at = 0.f;
  const unsigned short* base = h2b + ((size_t)b * NNODE_ + ch * 128) * DH_ + d;
  for (int n = 0; n < 128; n++) {
    float x = bf2f(base[(size_t)n * DH_]);
    int lab = slab[n];
    at += x;
#pragma unroll
    for (int k = 0; k < C_; k++) a[k] += (lab == k) ? x : 0.f;
  }
  float* pb = part + ((size_t)(ch * B_ + b) * 9) * DH_ + d;
#pragma unroll
  for (int k = 0; k < C_; k++) pb[(size_t)k * DH_] = a[k];
  pb[(size_t)8 * DH_] = at;
}

__global__ __launch_bounds__(256) void pool_fin(const float* __restrict__ part,
                                                const int* __restrict__ node_label,
                                                const int* __restrict__ feat_label,
                                                float* __restrict__ poolv,
                                                float* __restrict__ hg_raw) {
  int b = blockIdx.x, d = threadIdx.x;
  __shared__ int cnt[C_];
  if (d < C_) cnt[d] = 0;
  __syncthreads();
  for (int n = d; n < NNODE_; n += 256) atomicAdd(&cnt[node_label[n]], 1);
  __syncthreads();
  float s[9];
#pragma unroll
  for (int k = 0; k < 9; k++) s[k] = 0.f;
  for (int ch = 0; ch < 8; ch++) {
    const float* pb = part + ((size_t)(ch * B_ + b) * 9) * DH_ + d;
#pragma unroll
    for (int k = 0; k < 9; k++) s[k] += pb[(size_t)k * DH_];
  }
  int fl = feat_label[d];
#pragma unroll
  for (int k = 0; k < C_; k++) {
    float cntf = fmaxf((float)cnt[k], 1.f);
    float v = (fl == k) ? (s[k] / cntf) : 0.f;
    poolv[((size_t)k * B_ + b) * DH_ + d] = v;
  }
  hg_raw[(size_t)b * DH_ + d] = s[8] * (1.f / NNODE_);
}

// ---------------- tail ----------------

// fused resize + qkv: grid B*C
__global__ __launch_bounds__(256) void rq_t(const float* __restrict__ poolv,
                                            const float* __restrict__ Wrt,
                                            const float* __restrict__ br,
                                            const float* __restrict__ Wq,
                                            const float* __restrict__ Wk,
                                            const float* __restrict__ Wv,
                                            float* __restrict__ emb,
                                            float* __restrict__ q, float* __restrict__ k,
                                            float* __restrict__ v) {
  int key = blockIdx.x & 7, b = blockIdx.x >> 3, t = threadIdx.x;
  __shared__ float pl[DH_], es[DH_];
  pl[t] = poolv[((size_t)key * B_ + b) * DH_ + t];
  __syncthreads();
  const float* W = Wrt + (size_t)key * DH_ * DH_;
  float s = 0.f;
  for (int d = 0; d < DH_; d++) s += pl[d] * W[d * DH_ + t];
  s += br[key * DH_ + t];
  es[t] = s;
  size_t idx = (size_t)b * C_ + key;
  emb[idx * DH_ + t] = s;
  __syncthreads();
  float sq = 0.f, sk = 0.f, sv = 0.f;
  for (int kk = 0; kk < DH_; kk++) {
    float xv = es[kk];
    sq += xv * Wq[kk * DH_ + t];
    sk += xv * Wk[kk * DH_ + t];
    sv += xv * Wv[kk * DH_ + t];
  }
  q[idx * DH_ + t] = sq;
  k[idx * DH_ + t] = sk;
  v[idx * DH_ + t] = sv;
}

__global__ __launch_bounds__(256) void attn_core(const float* __restrict__ q,
                                                 const float* __restrict__ k,
                                                 const float* __restrict__ v,
                                                 float* __restrict__ osb) {
  int b = blockIdx.x, t = threadIdx.x;
  __shared__ float qs[C_][DH_], ks[C_][DH_], vs[C_][DH_];
  __shared__ float sc[H_][C_][C_];
  for (int c = 0; c < C_; c++) {
    qs[c][t] = q[((size_t)b * C_ + c) * DH_ + t];
    ks[c][t] = k[((size_t)b * C_ + c) * DH_ + t];
    vs[c][t] = v[((size_t)b * C_ + c) * DH_ + t];
  }
  __syncthreads();
  for (int idx = t; idx < H_ * C_ * C_; idx += 256) {
    int hh = idx / (C_ * C_);
    int qc = (idx / C_) % C_;
    int kc = idx % C_;
    float s = 0.f;
    for (int dd = 0; dd < 32; dd++) s += qs[qc][hh * 32 + dd] * ks[kc][hh * 32 + dd];
    sc[hh][qc][kc] = s * 0.35355339059327373f;
  }
  __syncthreads();
  if (t < H_ * C_) {
    int hh = t / C_, qc = t % C_;
    float m = -1e30f;
    for (int kc = 0; kc < C_; kc++) m = fmaxf(m, sc[hh][qc][kc]);
    float sum = 0.f;
    for (int kc = 0; kc < C_; kc++) { float e = expf(sc[hh][qc][kc] - m); sc[hh][qc][kc] = e; sum += e; }
    float inv = 1.f / sum;
    for (int kc = 0; kc < C_; kc++) sc[hh][qc][kc] *= inv;
  }
  __syncthreads();
  int hh = t >> 5;
  for (int c = 0; c < C_; c++) {
    float s = 0.f;
#pragma unroll
    for (int kc = 0; kc < C_; kc++) s += sc[hh][c][kc] * vs[kc][t];
    osb[((size_t)b * C_ + c) * DH_ + t] = s;
  }
}

__global__ __launch_bounds__(256) void ff_res(const float* __restrict__ osb,
                                              const float* __restrict__ emb,
                                              const float* __restrict__ lwt,
                                              const float* __restrict__ lb,
                                              float* __restrict__ ffb) {
  int idx = blockIdx.x, t = threadIdx.x;
  __shared__ float ox[DH_];
  ox[t] = osb[(size_t)idx * DH_ + t];
  __syncthreads();
  float s = 0.f;
  for (int d = 0; d < DH_; d++) s += ox[d] * lwt[d * DH_ + t];
  ffb[(size_t)idx * DH_ + t] =
      fmaxf(s + lb[t], 0.f) + ox[t] + emb[(size_t)idx * DH_ + t];
}

__global__ __launch_bounds__(256) void tail_final(
    const float* __restrict__ ffb, const float* __restrict__ hg_raw,
    const float* __restrict__ g, const float* __restrict__ be,
    const float* __restrict__ cw, const float* __restrict__ cb,
    float* __restrict__ out) {
  int t = threadIdx.x;
  __shared__ float hgn[B_][DH_];
  __shared__ float red[256];
  float gcol[B_];
  float mu = 0.f;
#pragma unroll
  for (int b = 0; b < B_; b++) {
    float s = 0.f;
    for (int c = 0; c < C_; c++) s += ffb[((size_t)b * C_ + c) * DH_ + t];
    gcol[b] = s * (1.f / C_);
    mu += gcol[b];
  }
  mu *= (1.f / B_);
  float var = 0.f;
#pragma unroll
  for (int b = 0; b < B_; b++) { float x = gcol[b] - mu; var += x * x; }
  var *= (1.f / B_);
  float is = rsqrtf(var + 1e-5f);
  float gm = g[t], bt = be[t];
  float s = 0.f;
#pragma unroll
  for (int b = 0; b < B_; b++) {
    hgn[b][t] = (gcol[b] - mu) * is * gm + bt;
    float d = gcol[b] - hg_raw[b * DH_ + t] + 1e-6f;
    s += d * d;
  }
  red[t] = s;
  __syncthreads();
  for (int w = 128; w > 0; w >>= 1) {
    if (t < w) red[t] += red[t + w];
    __syncthreads();
  }
  if (t == 0) out[B_ * NCLS_] = sqrtf(red[0]);
  for (int o = t; o < B_ * NCLS_; o += 256) {
    int b = o / NCLS_, j = o % NCLS_;
    float sl = cb[j];
    for (int d = 0; d < DH_; d++) sl += hgn[b][d] * cw[j * DH_ + d];
    out[o] = sl;
  }
}

// ---------------- launch ----------------

extern "C" void kernel_launch(void* const* d_in, const int* in_sizes, int n_in,
                              void* d_out, int out_size, void* d_ws, size_t ws_size,
                              hipStream_t stream) {
  const float* h   = (const float*)d_in[0];
  const int* src   = (const int*)d_in[1];
  const int* dst   = (const int*)d_in[2];
  const int* nlab  = (const int*)d_in[3];
  const int* flab  = (const int*)d_in[4];
  const float* W1  = (const float*)d_in[5];
  const float* b1  = (const float*)d_in[6];
  const float* W2  = (const float*)d_in[7];
  const float* b2  = (const float*)d_in[8];
  const float* Wr  = (const float*)d_in[9];
  const float* br  = (const float*)d_in[10];
  const float* Wq  = (const float*)d_in[11];
  const float* Wk  = (const float*)d_in[12];
  const float* Wv  = (const float*)d_in[13];
  const float* lw  = (const float*)d_in[14];
  const float* lb  = (const float*)d_in[15];
  const float* bng = (const float*)d_in[16];
  const float* bnb = (const float*)d_in[17];
  const float* cw  = (const float*)d_in[18];
  const float* cb  = (const float*)d_in[19];
  float* out = (float*)d_out;

  char* p = (char*)d_ws;
  auto alloc = [&](size_t bytes) -> void* {
    void* q = (void*)p;
    p += (bytes + 255) & ~(size_t)255;
    return q;
  };
  unsigned int* xq    = (unsigned int*)alloc((size_t)TOTAL_ * DH_);       // 8MB fp8
  unsigned int* h1q   = (unsigned int*)alloc((size_t)TOTAL_ * DH_);       // 8MB fp8
  unsigned short* h2b = (unsigned short*)alloc((size_t)TOTAL_ * DH_ * 2); // 16MB bf16
  unsigned int* aggQ  = (unsigned int*)alloc((size_t)TOTAL_ * 1024);      // 32MB fp8
  unsigned int* Wq1   = (unsigned int*)alloc((size_t)256 * 256 * 4);      // fp8 W1^T
  unsigned int* Wq2   = (unsigned int*)alloc((size_t)256 * 256 * 4);      // fp8 W2^T
  float* Wrt   = (float*)alloc((size_t)C_ * DH_ * DH_ * 4);
  float* lwt   = (float*)alloc((size_t)DH_ * DH_ * 4);
  float* bsum1 = (float*)alloc(DH_ * 4);
  float* bsum2 = (float*)alloc(DH_ * 4);
  int* cnt_in   = (int*)alloc((size_t)R_ * TOTAL_ * 4);
  float* rs_out = (float*)alloc((size_t)R_ * TOTAL_ * 4);
  float* rs_in  = (float*)alloc((size_t)R_ * TOTAL_ * 4);
  int* csr_off  = (int*)alloc((size_t)R_ * (TOTAL_ + 1) * 4);
  int* csr_src  = (int*)alloc((size_t)R_ * E_ * 4);
  float* part   = (float*)alloc((size_t)8 * B_ * 9 * DH_ * 4);
  float* poolv  = (float*)alloc((size_t)C_ * B_ * DH_ * 4);
  float* hg_raw = (float*)alloc((size_t)B_ * DH_ * 4);
  float* emb    = (float*)alloc((size_t)B_ * C_ * DH_ * 4);
  float* qb     = (float*)alloc((size_t)B_ * C_ * DH_ * 4);
  float* kb     = (float*)alloc((size_t)B_ * C_ * DH_ * 4);
  float* vb     = (float*)alloc((size_t)B_ * C_ * DH_ * 4);
  float* osb    = (float*)alloc((size_t)B_ * C_ * DH_ * 4);
  float* ffb    = (float*)alloc((size_t)B_ * C_ * DH_ * 4);

  // prep-phase scratch aliased onto aggQ (dead until aggregation)
  unsigned int* parts = aggQ;                                                   // 16MB
  unsigned int* sbb   = (unsigned int*)((char*)aggQ + (size_t)16 * 1024 * 1024); // 16MB

  // graph prep (no global atomics)
  hist_part<<<dim3(S_, R_), 1024, 0, stream>>>(src, dst, parts);
  reduce_deg<<<R_ * TOTAL_ / 512, 256, 0, stream>>>(parts, rs_out, rs_in, cnt_in);
  scan_counts<<<R_, 1024, 0, stream>>>(cnt_in, csr_off);
  base_gen<<<R_ * TOTAL_ / 512, 256, 0, stream>>>(parts, csr_off, sbb);
  scatter_csr<<<dim3(S_, R_), 1024, 0, stream>>>(src, dst, sbb, csr_src);

  // weight/bias/input prep
  wconv_f8<<<512, 256, 0, stream>>>(W1, W2, Wq1, Wq2);
  bias_sum2<<<2, 256, 0, stream>>>(b1, b2, bsum1, bsum2);
  transpose_mats<<<9 * 256, 256, 0, stream>>>(Wr, lw, Wrt, lwt);
  hconv8<<<TOTAL_ * DH_ / 8 / 256, 256, 0, stream>>>(h, xq);

  // layer 1
  aggregate_f8<<<dim3(TOTAL_ / 8, R_), 256, 0, stream>>>(xq, csr_off, csr_src, rs_out, rs_in, aggQ);
  gemm_f8<0><<<dim3(TOTAL_ / 128, 2), 256, 0, stream>>>(
      (const unsigned char*)aggQ, (const unsigned char*)Wq1, bsum1,
      (unsigned char*)h1q, nullptr);

  // layer 2
  aggregate_f8<<<dim3(TOTAL_ / 8, R_), 256, 0, stream>>>(h1q, csr_off, csr_src, rs_out, rs_in, aggQ);
  gemm_f8<1><<<dim3(TOTAL_ / 128, 2), 256, 0, stream>>>(
      (const unsigned char*)aggQ, (const unsigned char*)Wq2, bsum2,
      nullptr, h2b);

  // pooling + tail
  pool_part<<<dim3(B_, 8), 256, 0, stream>>>(h2b, nlab, part);
  pool_fin<<<B_, 256, 0, stream>>>(part, nlab, flab, poolv, hg_raw);
  rq_t<<<B_ * C_, 256, 0, stream>>>(poolv, Wrt, br, Wq, Wk, Wv, emb, qb, kb, vb);
  attn_core<<<B_, 256, 0, stream>>>(qb, kb, vb, osb);
  ff_res<<<B_ * C_, 256, 0, stream>>>(osb, emb, lwt, lb, ffb);
  tail_final<<<1, 256, 0, stream>>>(ffb, hg_raw, bng, bnb, cw, cb, out);
}